// Round 3
// baseline (541.118 us; speedup 1.0000x reference)
//
#include <hip/hip_runtime.h>

// ---------------------------------------------------------------------------
// CausalSelfAttention2: x@Wqkv -> rope+scramble -> 512x block-causal attn
//                        -> o@Wo ; plus learned time-pooled qb/kb/vb outputs.
// Sizes: B=4 T=4096 C=1024 H=16 G=8 HS=64 GT=512. d_out is FLOAT32.
// R9: rope VALUES untouched (R3/R6 register form, validated; readback-phase
// rope is confirmed-broken, never retry). Two epilogue cost cuts:
//  (a) fc/fs accessed via TRANSPOSED tables fcT/fsT[32][4096] (built by tiny
//      f32 transpose kernels into d_out scratch, dead until gemm2) so the
//      4 consecutive t's of the r-loop load as ONE float4 per table.
//      Same f32 values, same fmaf order -> bit-identical rope.
//  (b) restage barriers removed: each wave restages through its PRIVATE Es
//      slice; intra-wave LDS write->read order is guaranteed.
// ---------------------------------------------------------------------------

typedef float  float4_t  __attribute__((ext_vector_type(4)));
typedef short  bfrag     __attribute__((ext_vector_type(8)));   // 8 bf16
typedef unsigned short ushort8 __attribute__((ext_vector_type(8)));

#define MFMA_BF16(A, B, C) __builtin_amdgcn_mfma_f32_16x16x32_bf16((A), (B), (C), 0, 0, 0)

__device__ __forceinline__ unsigned short f2bf(float f) {
  union { float f; unsigned u; } v; v.f = f;
  return (unsigned short)((v.u + 0x7FFFu + ((v.u >> 16) & 1u)) >> 16);   // RNE
}
__device__ __forceinline__ float bf2f(unsigned short h) {
  union { unsigned u; float f; } v; v.u = ((unsigned)h) << 16; return v.f;
}
// async global->LDS, 16B per lane; LDS dest = wave-uniform base + lane*16
__device__ __forceinline__ void async16(const void* g, void* l) {
  __builtin_amdgcn_global_load_lds(
      (const __attribute__((address_space(1))) unsigned int*)(unsigned long long)g,
      (__attribute__((address_space(3))) unsigned int*)(unsigned long long)l,
      16, 0, 0);
}

// ---------------------------------------------------------------------------
// f32 -> bf16 convert (8 elems/thread)
__global__ __launch_bounds__(256) void cvt_kernel(const float* __restrict__ in,
                                                  unsigned short* __restrict__ out, int n8) {
  int i = blockIdx.x * 256 + threadIdx.x;
  if (i >= n8) return;
  const float4_t* p = (const float4_t*)in + (size_t)i * 2;
  float4_t a = p[0], c = p[1];
  ushort8 r;
  r[0] = f2bf(a[0]); r[1] = f2bf(a[1]); r[2] = f2bf(a[2]); r[3] = f2bf(a[3]);
  r[4] = f2bf(c[0]); r[5] = f2bf(c[1]); r[6] = f2bf(c[2]); r[7] = f2bf(c[3]);
  *((ushort8*)out + i) = r;
}

// out[n][k] = bf16(in[k][n]);  in is [R,C] f32, out is [C,R] bf16
__global__ void transpose_cvt_kernel(const float* __restrict__ in,
                                     unsigned short* __restrict__ out, int R, int C) {
  __shared__ float t[32][33];
  int bc = blockIdx.x * 32, br = blockIdx.y * 32;
  int x = threadIdx.x, y = threadIdx.y;
  for (int i = 0; i < 32; i += 8) t[y + i][x] = in[(size_t)(br + y + i) * C + bc + x];
  __syncthreads();
  for (int i = 0; i < 32; i += 8) out[(size_t)(bc + y + i) * R + br + x] = f2bf(t[x][y + i]);
}

// out[n][k] = in[k][n];  pure f32 transpose (for fc/fs -> fcT/fsT)
__global__ void transpose_f32_kernel(const float* __restrict__ in,
                                     float* __restrict__ out, int R, int C) {
  __shared__ float t[32][33];
  int bc = blockIdx.x * 32, br = blockIdx.y * 32;
  int x = threadIdx.x, y = threadIdx.y;
  for (int i = 0; i < 32; i += 8) t[y + i][x] = in[(size_t)(br + y + i) * C + bc + x];
  __syncthreads();
  for (int i = 0; i < 32; i += 8) out[(size_t)(bc + y + i) * R + br + x] = t[x][y + i];
}

// ---------------------------------------------------------------------------
// Shared GEMM core: C128x128 tile, BK=32, 4 waves (each 64x64 = 4x4 mfma frags)
// A [M,K] bf16 row-major, BT [N,K] bf16 row-major. XOR-swizzled LDS (2-way max).
__device__ __forceinline__ void gemm_core(const unsigned short* __restrict__ A,
                                          const unsigned short* __restrict__ BT,
                                          int bm0, int bn0, int K,
                                          unsigned short* As, unsigned short* Bs,
                                          float4_t acc[4][4]) {
  int tid = threadIdx.x, w = tid >> 6;
  int lane = tid & 63, quad = lane >> 4, l16 = lane & 15;
  int wm = w >> 1, wn = w & 1;
  int rr = tid >> 2, xx = tid & 3;
  for (int k0 = 0; k0 < K; k0 += 32) {
    __syncthreads();
    {
      int r0 = rr,       s0 = xx ^ ((r0 >> 1) & 3);
      int r1 = rr + 64,  s1 = xx ^ ((r1 >> 1) & 3);
      async16(&A [(size_t)(bm0 + r0) * K + k0 + s0 * 8], &As[(size_t)(w * 64) * 8]);
      async16(&A [(size_t)(bm0 + r1) * K + k0 + s1 * 8], &As[(size_t)(256 + w * 64) * 8]);
      async16(&BT[(size_t)(bn0 + r0) * K + k0 + s0 * 8], &Bs[(size_t)(w * 64) * 8]);
      async16(&BT[(size_t)(bn0 + r1) * K + k0 + s1 * 8], &Bs[(size_t)(256 + w * 64) * 8]);
    }
    __syncthreads();
    bfrag af[4], bf_[4];
    for (int i = 0; i < 4; ++i) {
      int rm = wm * 64 + i * 16 + l16;
      af[i]  = *(const bfrag*)&As[(size_t)(rm * 4 + (quad ^ ((rm >> 1) & 3))) * 8];
      int rn = wn * 64 + i * 16 + l16;
      bf_[i] = *(const bfrag*)&Bs[(size_t)(rn * 4 + (quad ^ ((rn >> 1) & 3))) * 8];
    }
    for (int i = 0; i < 4; ++i)
      for (int j = 0; j < 4; ++j)
        acc[i][j] = MFMA_BF16(af[i], bf_[j], acc[i][j]);
  }
}

// GEMM1: qkv = x @ Wqkv. Rope applied in-register (R3-validated shfl form;
// fc/fs values now read from transposed tables -> float4 loads, identical f32
// values & fma order), then LDS restage (placement validated) + vector stores.
__global__ __launch_bounds__(256) void gemm1_kernel(const unsigned short* __restrict__ xb,
    const unsigned short* __restrict__ wqkvT,
    const float* __restrict__ fcT, const float* __restrict__ fsT,
    unsigned short* __restrict__ q5, unsigned short* __restrict__ k5,
    unsigned short* __restrict__ v5) {
  __shared__ __align__(16) unsigned short As[128 * 32];
  __shared__ __align__(16) unsigned short Bs[128 * 32];
  __shared__ __align__(16) float Es[4 * 1088];               // 4 waves x (16 rows * 68)
  float4_t acc[4][4];
  for (int i = 0; i < 4; ++i) for (int j = 0; j < 4; ++j)
    acc[i][j] = (float4_t){0.f, 0.f, 0.f, 0.f};
  int bn0 = blockIdx.x * 128, bm0 = blockIdx.y * 128;
  gemm_core(xb, wqkvT, bm0, bn0, 1024, As, Bs, acc);

  int tid = threadIdx.x, w = tid >> 6, lane = tid & 63, quad = lane >> 4, l16 = lane & 15;
  int wm = w >> 1, wn = w & 1;

  // ---- rope in registers (R3 numerics; fcT/fsT float4 loads over r) -------
  for (int i = 0; i < 4; ++i) {
    int t0 = (bm0 + wm * 64 + i * 16 + quad * 4) & 4095;   // r spans t0..t0+3
    for (int j = 0; j < 4; ++j) {
      int gcol = bn0 + wn * 64 + j * 16 + l16;    // wave-uniform branch (16-aligned)
      if (gcol < 2048) {
        int ci = (gcol & 63) >> 1;                // pair index 0..31 (per lane)
        const float4_t c4 = *(const float4_t*)&fcT[(size_t)ci * 4096 + t0];
        const float4_t s4 = *(const float4_t*)&fsT[(size_t)ci * 4096 + t0];
        for (int r = 0; r < 4; ++r) {
          float val = acc[i][j][r];
          float partner = __shfl_xor(val, 1);     // even<->odd channel pair
          float c = c4[r], s = s4[r];             // == fc[t*32+ci], fs[t*32+ci]
          acc[i][j][r] = (gcol & 1) ? fmaf(partner, s, val * c)
                                    : fmaf(-partner, s, val * c);
        }
      }
    }
  }

  // ---- LDS restage (placement-validated) + full-line vector stores --------
  // Each wave uses its PRIVATE Es slice; intra-wave LDS write->read order is
  // architectural, so no barriers are needed here.
  float* slice = &Es[w * 1088];
  for (int i = 0; i < 4; ++i) {
    for (int j = 0; j < 4; ++j)
      for (int r = 0; r < 4; ++r)
        slice[(quad * 4 + r) * 68 + j * 16 + l16] = acc[i][j][r];
    for (int m = 0; m < 2; ++m) {
      int rl = m * 8 + (lane >> 3);               // 0..15 local row
      int cb = (lane & 7) * 8;                    // 8-aligned col base
      const float* rp = &slice[rl * 68 + cb];
      ushort8 outv;
      outv[0] = f2bf(rp[0]); outv[1] = f2bf(rp[1]);
      outv[2] = f2bf(rp[2]); outv[3] = f2bf(rp[3]);
      outv[4] = f2bf(rp[4]); outv[5] = f2bf(rp[5]);
      outv[6] = f2bf(rp[6]); outv[7] = f2bf(rp[7]);
      int grow = bm0 + wm * 64 + i * 16 + rl;     // = b*4096 + t
      int b = grow >> 12, t = grow & 4095;
      int gcol = bn0 + wn * 64 + cb;              // 0..3071, 8-aligned
      if (gcol < 2048) {                          // q or k: scramble
        int cc = gcol & 1023;
        int ho = cc >> 6, hs0 = cc & 63;
        // [B,H,T,HS] raw-view [B,G,GT,H,HS]: g=ho/2, gt=(ho&1)*256+t/16, h=t&15
        size_t idx = ((((size_t)b * 16 + (t & 15)) * 8 + (ho >> 1)) * 512 +
                      (((ho & 1) << 8) | (t >> 4))) * 64 + hs0;
        if (gcol < 1024) *(ushort8*)&q5[idx] = outv;
        else             *(ushort8*)&k5[idx] = outv;
      } else {                                    // v: natural split
        int cc = gcol - 2048;
        size_t idx = ((((size_t)b * 16 + (cc >> 6)) * 8 + (t >> 9)) * 512 +
                      (t & 511)) * 64 + (cc & 63);
        *(ushort8*)&v5[idx] = outv;
      }
    }
  }
}

// GEMM2: out = o @ Wo, f32 store into d_out[0 .. 16777216)
__global__ __launch_bounds__(256) void gemm2_kernel(const unsigned short* __restrict__ ob,
    const unsigned short* __restrict__ woT, float* __restrict__ outp) {
  __shared__ __align__(16) unsigned short As[128 * 32];
  __shared__ __align__(16) unsigned short Bs[128 * 32];
  float4_t acc[4][4];
  for (int i = 0; i < 4; ++i) for (int j = 0; j < 4; ++j)
    acc[i][j] = (float4_t){0.f, 0.f, 0.f, 0.f};
  int bn0 = blockIdx.x * 128, bm0 = blockIdx.y * 128;
  gemm_core(ob, woT, bm0, bn0, 1024, As, Bs, acc);
  int tid = threadIdx.x, w = tid >> 6, lane = tid & 63, quad = lane >> 4, l16 = lane & 15;
  int wm = w >> 1, wn = w & 1;
  for (int i = 0; i < 4; ++i)
    for (int j = 0; j < 4; ++j)
      for (int r = 0; r < 4; ++r)
        outp[(size_t)(bm0 + wm * 64 + i * 16 + quad * 4 + r) * 1024 +
             bn0 + wn * 64 + j * 16 + l16] = acc[i][j][r];
}

// ---------------------------------------------------------------------------
// MFMA flash attention per (b,h,g) block of 512, 64-query tile / wg, 16 q/wave.
// Validated end-to-end by R4/R5 output-0 pass.
__global__ __launch_bounds__(256) void attn_kernel(const unsigned short* __restrict__ q5,
    const unsigned short* __restrict__ k5, const unsigned short* __restrict__ v5,
    unsigned short* __restrict__ ob) {
  __shared__ __align__(16) unsigned short Ks[32 * 64];       // swizzled 16B slots
  __shared__ __align__(16) unsigned short VTs[64 * 72];      // [hs][key], pad->72
  __shared__ __align__(16) unsigned short Ps[4 * 16 * 40];   // per-wave P, pad->40
  int bx = blockIdx.x;
  int qt = bx & 7, g = (bx >> 3) & 7, h = (bx >> 6) & 15, b = bx >> 10;
  int tid = threadIdx.x, w = tid >> 6, lane = tid & 63, quad = lane >> 4, l16 = lane & 15;
  size_t base = ((((size_t)b * 16 + h) * 8 + g) * 512) * 64;
  const unsigned short* Q = q5 + base;
  const unsigned short* K = k5 + base;
  const unsigned short* V = v5 + base;

  int qrow = qt * 64 + w * 16 + l16;
  bfrag qf0 = *(const bfrag*)&Q[(size_t)qrow * 64 + quad * 8];
  bfrag qf1 = *(const bfrag*)&Q[(size_t)qrow * 64 + 32 + quad * 8];

  float4_t acc[4];
  for (int i = 0; i < 4; ++i) acc[i] = (float4_t){0.f, 0.f, 0.f, 0.f};
  float m_i[4] = {-1e30f, -1e30f, -1e30f, -1e30f};
  float l_i[4] = {0.f, 0.f, 0.f, 0.f};

  int skey = tid >> 3, sx = tid & 7, ss = sx ^ (skey & 7);   // K staging swizzle
  unsigned short* Pw = &Ps[w * 640];
  int ntiles = qt * 2 + 2;

  for (int kt = 0; kt < ntiles; ++kt) {
    __syncthreads();
    // K tile 32x64: one async16 per thread
    async16(&K[(size_t)(kt * 32 + skey) * 64 + ss * 8], &Ks[(size_t)(w * 64) * 8]);
    // V tile transposed into VTs[hs][key] (threads 0..127, 2 keys x 8 hs each)
    if (tid < 128) {
      int kp = tid & 15, hsg = tid >> 4;
      const unsigned short* vp0 = &V[(size_t)(kt * 32 + kp * 2) * 64 + hsg * 8];
      ushort8 va = *(const ushort8*)vp0;
      ushort8 vb = *(const ushort8*)(vp0 + 64);
      for (int e = 0; e < 8; ++e) {
        unsigned pk = (unsigned)va[e] | ((unsigned)vb[e] << 16);
        *(unsigned*)&VTs[(size_t)(hsg * 8 + e) * 72 + kp * 2] = pk;
      }
    }
    __syncthreads();

    float4_t s0 = (float4_t){0.f, 0.f, 0.f, 0.f};
    float4_t s1 = (float4_t){0.f, 0.f, 0.f, 0.f};
    {
      int sl0 = l16 * 8 + (quad ^ (l16 & 7));          // hs 0..31
      s0 = MFMA_BF16(qf0, *(const bfrag*)&Ks[(size_t)sl0 * 8], s0);
      s1 = MFMA_BF16(qf0, *(const bfrag*)&Ks[(size_t)(sl0 + 128) * 8], s1);
      int sl1 = l16 * 8 + ((4 + quad) ^ (l16 & 7));    // hs 32..63
      s0 = MFMA_BF16(qf1, *(const bfrag*)&Ks[(size_t)sl1 * 8], s0);
      s1 = MFMA_BF16(qf1, *(const bfrag*)&Ks[(size_t)(sl1 + 128) * 8], s1);
    }

    int qa = qt * 64 + w * 16 + quad * 4;
    int kb0 = kt * 32 + l16;
    for (int r = 0; r < 4; ++r) {
      float v0 = s0[r] * 0.125f, v1 = s1[r] * 0.125f;
      if (kb0 > qa + r)      v0 = -1e30f;
      if (kb0 + 16 > qa + r) v1 = -1e30f;
      float tm = fmaxf(v0, v1);
      tm = fmaxf(tm, __shfl_xor(tm, 1));
      tm = fmaxf(tm, __shfl_xor(tm, 2));
      tm = fmaxf(tm, __shfl_xor(tm, 4));
      tm = fmaxf(tm, __shfl_xor(tm, 8));
      float nm = fmaxf(m_i[r], tm);
      float alpha = __expf(m_i[r] - nm);
      m_i[r] = nm;
      float p0 = __expf(v0 - nm), p1 = __expf(v1 - nm);
      float rs = p0 + p1;
      rs += __shfl_xor(rs, 1);
      rs += __shfl_xor(rs, 2);
      rs += __shfl_xor(rs, 4);
      rs += __shfl_xor(rs, 8);
      l_i[r] = l_i[r] * alpha + rs;
      acc[0][r] *= alpha; acc[1][r] *= alpha; acc[2][r] *= alpha; acc[3][r] *= alpha;
      Pw[(quad * 4 + r) * 40 + l16] = f2bf(p0);
      Pw[(quad * 4 + r) * 40 + 16 + l16] = f2bf(p1);
    }
    __syncthreads();   // P writes visible before A-frag reads
    // P (C-layout) -> A-operand frag via LDS round-trip
    bfrag pf = *(const bfrag*)&Pw[(size_t)l16 * 40 + quad * 8];
    for (int ht = 0; ht < 4; ++ht) {
      bfrag vf = *(const bfrag*)&VTs[(size_t)(ht * 16 + l16) * 72 + quad * 8];
      acc[ht] = MFMA_BF16(pf, vf, acc[ht]);
    }
  }

  // o_final[b, g*512+gt, h*64+hs]
  int orow = b * 4096 + g * 512 + qt * 64 + w * 16 + quad * 4;
  for (int ht = 0; ht < 4; ++ht)
    for (int r = 0; r < 4; ++r)
      ob[(size_t)(orow + r) * 1024 + h * 64 + ht * 16 + l16] = f2bf(acc[ht][r] / l_i[r]);
}

// ---------------------------------------------------------------------------
// qb/kb/vb: weighted sums over gt (causal_attn on 1x1 == identity => vb pooled)
// 1024 threads/block, 16-way t-split + LDS reduce (validated R8).
__global__ __launch_bounds__(1024) void pools_kernel(const unsigned short* __restrict__ q5,
    const unsigned short* __restrict__ k5, const unsigned short* __restrict__ v5,
    const float* __restrict__ qp, const float* __restrict__ kp,
    const float* __restrict__ vp, float* __restrict__ outp) {
  __shared__ float red[3][16][64];
  int g = blockIdx.x, h = blockIdx.y, b = blockIdx.z;
  int hs = threadIdx.x & 63, tc = threadIdx.x >> 6;      // 16 chunks x 32 t
  size_t base = ((((size_t)b * 16 + h) * 8 + g) * 512) * 64 + hs;
  float aq = 0.f, ak = 0.f, av = 0.f;
  int t0 = tc * 32;
  for (int t = t0; t < t0 + 32; ++t) {
    size_t o = base + (size_t)t * 64;
    aq = fmaf(bf2f(q5[o]), qp[t], aq);
    ak = fmaf(bf2f(k5[o]), kp[t], ak);
    av = fmaf(bf2f(v5[o]), vp[t], av);
  }
  red[0][tc][hs] = aq;
  red[1][tc][hs] = ak;
  red[2][tc][hs] = av;
  __syncthreads();
  if (tc < 3) {                                          // tc: 0=q 1=k 2=v
    float a = 0.f;
    for (int c = 0; c < 16; ++c) a += red[tc][c][hs];
    size_t oi = (((size_t)b * 16 + h) * 7 + g) * 64 + hs;
    size_t off = (tc == 0) ? 0 : (tc == 1) ? 28672 : 57344;
    outp[16777216 + off + oi] = a;
  }
}

// ---------------------------------------------------------------------------
extern "C" void kernel_launch(void* const* d_in, const int* in_sizes, int n_in,
                              void* d_out, int out_size, void* d_ws, size_t ws_size,
                              hipStream_t stream) {
  (void)in_sizes; (void)n_in; (void)out_size; (void)ws_size;
  const float* x    = (const float*)d_in[0];
  const float* Wqkv = (const float*)d_in[1];
  const float* Wo   = (const float*)d_in[2];
  const float* qp   = (const float*)d_in[3];
  const float* kp   = (const float*)d_in[4];
  const float* vp   = (const float*)d_in[5];
  const float* fc   = (const float*)d_in[6];
  const float* fs   = (const float*)d_in[7];
  float* outp = (float*)d_out;                     // f32 output (reference dtype)

  char* ws = (char*)d_ws;                          // 136 MiB used
  unsigned short* xb    = (unsigned short*)(ws);               // 33.5MB (o aliases it later)
  unsigned short* wqkvT = (unsigned short*)(ws + 33554432);    // 6.3MB
  unsigned short* woT   = (unsigned short*)(ws + 39845888);    // 2.1MB
  unsigned short* q5    = (unsigned short*)(ws + 41943040);    // 33.5MB
  unsigned short* k5    = (unsigned short*)(ws + 75497472);    // 33.5MB
  unsigned short* v5    = (unsigned short*)(ws + 109051904);   // 33.5MB
  unsigned short* ob    = xb;  // safe alias: xb fully consumed by gemm1 before attn writes

  // fcT/fsT scratch lives in d_out[0 .. 512K floats): dead until gemm2, which
  // runs LAST and overwrites it. 32x4096 f32 each.
  float* fcT = outp;
  float* fsT = outp + 131072;

  cvt_kernel<<<8192, 256, 0, stream>>>(x, xb, 2097152);
  transpose_cvt_kernel<<<dim3(96, 32), dim3(32, 8), 0, stream>>>(Wqkv, wqkvT, 1024, 3072);
  transpose_cvt_kernel<<<dim3(32, 32), dim3(32, 8), 0, stream>>>(Wo, woT, 1024, 1024);
  transpose_f32_kernel<<<dim3(1, 128), dim3(32, 8), 0, stream>>>(fc, fcT, 4096, 32);
  transpose_f32_kernel<<<dim3(1, 128), dim3(32, 8), 0, stream>>>(fs, fsT, 4096, 32);
  gemm1_kernel<<<dim3(24, 128), 256, 0, stream>>>(xb, wqkvT, fcT, fsT, q5, k5, v5);
  attn_kernel<<<4096, 256, 0, stream>>>(q5, k5, v5, ob);
  pools_kernel<<<dim3(7, 16, 4), 1024, 0, stream>>>(q5, k5, v5, qp, kp, vp, outp);
  gemm2_kernel<<<dim3(8, 128), 256, 0, stream>>>(ob, woT, outp);
}

// Round 4
// 506.189 us; speedup vs baseline: 1.0690x; 1.0690x over previous
//
#include <hip/hip_runtime.h>

// ---------------------------------------------------------------------------
// CausalSelfAttention2: x@Wqkv -> rope+scramble -> 512x block-causal attn
//                        -> o@Wo ; plus learned time-pooled qb/kb/vb outputs.
// Sizes: B=4 T=4096 C=1024 H=16 G=8 HS=64 GT=512. d_out is FLOAT32.
// R10: attn KVBLK 32 -> 64. Softmax shfl-tree cost scales with #tiles, not
// #keys, so doubling the K/V tile halves the serial-latency-bound core
// (avg 9 -> 4.5 tiles/block), halves barriers+staging; MFMA count unchanged.
// Post-P barrier removed (Pw wave-private; intra-wave LDS order guaranteed —
// same validated argument as the R9 Es-restage change).
// gemm1/gemm2/pools untouched (R9-validated).
// ---------------------------------------------------------------------------

typedef float  float4_t  __attribute__((ext_vector_type(4)));
typedef short  bfrag     __attribute__((ext_vector_type(8)));   // 8 bf16
typedef unsigned short ushort8 __attribute__((ext_vector_type(8)));

#define MFMA_BF16(A, B, C) __builtin_amdgcn_mfma_f32_16x16x32_bf16((A), (B), (C), 0, 0, 0)

__device__ __forceinline__ unsigned short f2bf(float f) {
  union { float f; unsigned u; } v; v.f = f;
  return (unsigned short)((v.u + 0x7FFFu + ((v.u >> 16) & 1u)) >> 16);   // RNE
}
__device__ __forceinline__ float bf2f(unsigned short h) {
  union { unsigned u; float f; } v; v.u = ((unsigned)h) << 16; return v.f;
}
// async global->LDS, 16B per lane; LDS dest = wave-uniform base + lane*16
__device__ __forceinline__ void async16(const void* g, void* l) {
  __builtin_amdgcn_global_load_lds(
      (const __attribute__((address_space(1))) unsigned int*)(unsigned long long)g,
      (__attribute__((address_space(3))) unsigned int*)(unsigned long long)l,
      16, 0, 0);
}

// ---------------------------------------------------------------------------
// f32 -> bf16 convert (8 elems/thread)
__global__ __launch_bounds__(256) void cvt_kernel(const float* __restrict__ in,
                                                  unsigned short* __restrict__ out, int n8) {
  int i = blockIdx.x * 256 + threadIdx.x;
  if (i >= n8) return;
  const float4_t* p = (const float4_t*)in + (size_t)i * 2;
  float4_t a = p[0], c = p[1];
  ushort8 r;
  r[0] = f2bf(a[0]); r[1] = f2bf(a[1]); r[2] = f2bf(a[2]); r[3] = f2bf(a[3]);
  r[4] = f2bf(c[0]); r[5] = f2bf(c[1]); r[6] = f2bf(c[2]); r[7] = f2bf(c[3]);
  *((ushort8*)out + i) = r;
}

// out[n][k] = bf16(in[k][n]);  in is [R,C] f32, out is [C,R] bf16
__global__ void transpose_cvt_kernel(const float* __restrict__ in,
                                     unsigned short* __restrict__ out, int R, int C) {
  __shared__ float t[32][33];
  int bc = blockIdx.x * 32, br = blockIdx.y * 32;
  int x = threadIdx.x, y = threadIdx.y;
  for (int i = 0; i < 32; i += 8) t[y + i][x] = in[(size_t)(br + y + i) * C + bc + x];
  __syncthreads();
  for (int i = 0; i < 32; i += 8) out[(size_t)(bc + y + i) * R + br + x] = f2bf(t[x][y + i]);
}

// out[n][k] = in[k][n];  pure f32 transpose (for fc/fs -> fcT/fsT)
__global__ void transpose_f32_kernel(const float* __restrict__ in,
                                     float* __restrict__ out, int R, int C) {
  __shared__ float t[32][33];
  int bc = blockIdx.x * 32, br = blockIdx.y * 32;
  int x = threadIdx.x, y = threadIdx.y;
  for (int i = 0; i < 32; i += 8) t[y + i][x] = in[(size_t)(br + y + i) * C + bc + x];
  __syncthreads();
  for (int i = 0; i < 32; i += 8) out[(size_t)(bc + y + i) * R + br + x] = t[x][y + i];
}

// ---------------------------------------------------------------------------
// Shared GEMM core: C128x128 tile, BK=32, 4 waves (each 64x64 = 4x4 mfma frags)
// A [M,K] bf16 row-major, BT [N,K] bf16 row-major. XOR-swizzled LDS (2-way max).
__device__ __forceinline__ void gemm_core(const unsigned short* __restrict__ A,
                                          const unsigned short* __restrict__ BT,
                                          int bm0, int bn0, int K,
                                          unsigned short* As, unsigned short* Bs,
                                          float4_t acc[4][4]) {
  int tid = threadIdx.x, w = tid >> 6;
  int lane = tid & 63, quad = lane >> 4, l16 = lane & 15;
  int wm = w >> 1, wn = w & 1;
  int rr = tid >> 2, xx = tid & 3;
  for (int k0 = 0; k0 < K; k0 += 32) {
    __syncthreads();
    {
      int r0 = rr,       s0 = xx ^ ((r0 >> 1) & 3);
      int r1 = rr + 64,  s1 = xx ^ ((r1 >> 1) & 3);
      async16(&A [(size_t)(bm0 + r0) * K + k0 + s0 * 8], &As[(size_t)(w * 64) * 8]);
      async16(&A [(size_t)(bm0 + r1) * K + k0 + s1 * 8], &As[(size_t)(256 + w * 64) * 8]);
      async16(&BT[(size_t)(bn0 + r0) * K + k0 + s0 * 8], &Bs[(size_t)(w * 64) * 8]);
      async16(&BT[(size_t)(bn0 + r1) * K + k0 + s1 * 8], &Bs[(size_t)(256 + w * 64) * 8]);
    }
    __syncthreads();
    bfrag af[4], bf_[4];
    for (int i = 0; i < 4; ++i) {
      int rm = wm * 64 + i * 16 + l16;
      af[i]  = *(const bfrag*)&As[(size_t)(rm * 4 + (quad ^ ((rm >> 1) & 3))) * 8];
      int rn = wn * 64 + i * 16 + l16;
      bf_[i] = *(const bfrag*)&Bs[(size_t)(rn * 4 + (quad ^ ((rn >> 1) & 3))) * 8];
    }
    for (int i = 0; i < 4; ++i)
      for (int j = 0; j < 4; ++j)
        acc[i][j] = MFMA_BF16(af[i], bf_[j], acc[i][j]);
  }
}

// GEMM1: qkv = x @ Wqkv. Rope applied in-register (R3-validated shfl form;
// fc/fs values read from transposed tables -> float4 loads, identical f32
// values & fma order), then LDS restage (placement validated) + vector stores.
__global__ __launch_bounds__(256) void gemm1_kernel(const unsigned short* __restrict__ xb,
    const unsigned short* __restrict__ wqkvT,
    const float* __restrict__ fcT, const float* __restrict__ fsT,
    unsigned short* __restrict__ q5, unsigned short* __restrict__ k5,
    unsigned short* __restrict__ v5) {
  __shared__ __align__(16) unsigned short As[128 * 32];
  __shared__ __align__(16) unsigned short Bs[128 * 32];
  __shared__ __align__(16) float Es[4 * 1088];               // 4 waves x (16 rows * 68)
  float4_t acc[4][4];
  for (int i = 0; i < 4; ++i) for (int j = 0; j < 4; ++j)
    acc[i][j] = (float4_t){0.f, 0.f, 0.f, 0.f};
  int bn0 = blockIdx.x * 128, bm0 = blockIdx.y * 128;
  gemm_core(xb, wqkvT, bm0, bn0, 1024, As, Bs, acc);

  int tid = threadIdx.x, w = tid >> 6, lane = tid & 63, quad = lane >> 4, l16 = lane & 15;
  int wm = w >> 1, wn = w & 1;

  // ---- rope in registers (R3 numerics; fcT/fsT float4 loads over r) -------
  for (int i = 0; i < 4; ++i) {
    int t0 = (bm0 + wm * 64 + i * 16 + quad * 4) & 4095;   // r spans t0..t0+3
    for (int j = 0; j < 4; ++j) {
      int gcol = bn0 + wn * 64 + j * 16 + l16;    // wave-uniform branch (16-aligned)
      if (gcol < 2048) {
        int ci = (gcol & 63) >> 1;                // pair index 0..31 (per lane)
        const float4_t c4 = *(const float4_t*)&fcT[(size_t)ci * 4096 + t0];
        const float4_t s4 = *(const float4_t*)&fsT[(size_t)ci * 4096 + t0];
        for (int r = 0; r < 4; ++r) {
          float val = acc[i][j][r];
          float partner = __shfl_xor(val, 1);     // even<->odd channel pair
          float c = c4[r], s = s4[r];             // == fc[t*32+ci], fs[t*32+ci]
          acc[i][j][r] = (gcol & 1) ? fmaf(partner, s, val * c)
                                    : fmaf(-partner, s, val * c);
        }
      }
    }
  }

  // ---- LDS restage (placement-validated) + full-line vector stores --------
  // Each wave uses its PRIVATE Es slice; intra-wave LDS write->read order is
  // architectural, so no barriers are needed here.
  float* slice = &Es[w * 1088];
  for (int i = 0; i < 4; ++i) {
    for (int j = 0; j < 4; ++j)
      for (int r = 0; r < 4; ++r)
        slice[(quad * 4 + r) * 68 + j * 16 + l16] = acc[i][j][r];
    for (int m = 0; m < 2; ++m) {
      int rl = m * 8 + (lane >> 3);               // 0..15 local row
      int cb = (lane & 7) * 8;                    // 8-aligned col base
      const float* rp = &slice[rl * 68 + cb];
      ushort8 outv;
      outv[0] = f2bf(rp[0]); outv[1] = f2bf(rp[1]);
      outv[2] = f2bf(rp[2]); outv[3] = f2bf(rp[3]);
      outv[4] = f2bf(rp[4]); outv[5] = f2bf(rp[5]);
      outv[6] = f2bf(rp[6]); outv[7] = f2bf(rp[7]);
      int grow = bm0 + wm * 64 + i * 16 + rl;     // = b*4096 + t
      int b = grow >> 12, t = grow & 4095;
      int gcol = bn0 + wn * 64 + cb;              // 0..3071, 8-aligned
      if (gcol < 2048) {                          // q or k: scramble
        int cc = gcol & 1023;
        int ho = cc >> 6, hs0 = cc & 63;
        // [B,H,T,HS] raw-view [B,G,GT,H,HS]: g=ho/2, gt=(ho&1)*256+t/16, h=t&15
        size_t idx = ((((size_t)b * 16 + (t & 15)) * 8 + (ho >> 1)) * 512 +
                      (((ho & 1) << 8) | (t >> 4))) * 64 + hs0;
        if (gcol < 1024) *(ushort8*)&q5[idx] = outv;
        else             *(ushort8*)&k5[idx] = outv;
      } else {                                    // v: natural split
        int cc = gcol - 2048;
        size_t idx = ((((size_t)b * 16 + (cc >> 6)) * 8 + (t >> 9)) * 512 +
                      (t & 511)) * 64 + (cc & 63);
        *(ushort8*)&v5[idx] = outv;
      }
    }
  }
}

// GEMM2: out = o @ Wo, f32 store into d_out[0 .. 16777216)
__global__ __launch_bounds__(256) void gemm2_kernel(const unsigned short* __restrict__ ob,
    const unsigned short* __restrict__ woT, float* __restrict__ outp) {
  __shared__ __align__(16) unsigned short As[128 * 32];
  __shared__ __align__(16) unsigned short Bs[128 * 32];
  float4_t acc[4][4];
  for (int i = 0; i < 4; ++i) for (int j = 0; j < 4; ++j)
    acc[i][j] = (float4_t){0.f, 0.f, 0.f, 0.f};
  int bn0 = blockIdx.x * 128, bm0 = blockIdx.y * 128;
  gemm_core(ob, woT, bm0, bn0, 1024, As, Bs, acc);
  int tid = threadIdx.x, w = tid >> 6, lane = tid & 63, quad = lane >> 4, l16 = lane & 15;
  int wm = w >> 1, wn = w & 1;
  for (int i = 0; i < 4; ++i)
    for (int j = 0; j < 4; ++j)
      for (int r = 0; r < 4; ++r)
        outp[(size_t)(bm0 + wm * 64 + i * 16 + quad * 4 + r) * 1024 +
             bn0 + wn * 64 + j * 16 + l16] = acc[i][j][r];
}

// ---------------------------------------------------------------------------
// MFMA flash attention per (b,h,g) block of 512, 64-query tile / wg, 16 q/wave.
// R10: 64-key K/V tiles (was 32). Per tile: 8 QK MFMA + 8 PV MFMA, one
// softmax pass (4 rows x 4 key-slots), 2 barriers. ntiles = qt+1.
__global__ __launch_bounds__(256) void attn_kernel(const unsigned short* __restrict__ q5,
    const unsigned short* __restrict__ k5, const unsigned short* __restrict__ v5,
    unsigned short* __restrict__ ob) {
  __shared__ __align__(16) unsigned short Ks[64 * 64];       // 512 swizzled 16B slots
  __shared__ __align__(16) unsigned short VTs[64 * 72];      // [hs][key 0..63], pad->72
  __shared__ __align__(16) unsigned short Ps[4 * 16 * 72];   // per-wave P[16 q][64 k], pad->72
  int bx = blockIdx.x;
  int qt = bx & 7, g = (bx >> 3) & 7, h = (bx >> 6) & 15, b = bx >> 10;
  int tid = threadIdx.x, w = tid >> 6, lane = tid & 63, quad = lane >> 4, l16 = lane & 15;
  size_t base = ((((size_t)b * 16 + h) * 8 + g) * 512) * 64;
  const unsigned short* Q = q5 + base;
  const unsigned short* K = k5 + base;
  const unsigned short* V = v5 + base;

  int qrow = qt * 64 + w * 16 + l16;
  bfrag qf0 = *(const bfrag*)&Q[(size_t)qrow * 64 + quad * 8];
  bfrag qf1 = *(const bfrag*)&Q[(size_t)qrow * 64 + 32 + quad * 8];

  float4_t acc[4];
  for (int i = 0; i < 4; ++i) acc[i] = (float4_t){0.f, 0.f, 0.f, 0.f};
  float m_i[4] = {-1e30f, -1e30f, -1e30f, -1e30f};
  float l_i[4] = {0.f, 0.f, 0.f, 0.f};

  int skey = tid >> 3, sx = tid & 7, ss = sx ^ (skey & 7);   // K staging swizzle
  int kp = tid & 31, hsg = tid >> 5;                          // V staging split
  unsigned short* Pw = &Ps[w * 1152];
  int ntiles = qt + 1;

  for (int kt = 0; kt < ntiles; ++kt) {
    __syncthreads();
    // K tile 64x64: two async16 per thread (keys skey and skey+32; the XOR
    // swizzle index is identical for key+32 since (key+32)&7 == key&7).
    async16(&K[(size_t)(kt * 64 + skey) * 64 + ss * 8],      &Ks[(size_t)(w * 64) * 8]);
    async16(&K[(size_t)(kt * 64 + 32 + skey) * 64 + ss * 8], &Ks[(size_t)(256 + w * 64) * 8]);
    // V tile transposed into VTs[hs][key]: 256 threads, 2 keys x 8 hs each
    {
      const unsigned short* vp0 = &V[(size_t)(kt * 64 + kp * 2) * 64 + hsg * 8];
      ushort8 va = *(const ushort8*)vp0;
      ushort8 vb = *(const ushort8*)(vp0 + 64);
      for (int e = 0; e < 8; ++e) {
        unsigned pk = (unsigned)va[e] | ((unsigned)vb[e] << 16);
        *(unsigned*)&VTs[(size_t)(hsg * 8 + e) * 72 + kp * 2] = pk;
      }
    }
    __syncthreads();

    float4_t s0 = (float4_t){0.f, 0.f, 0.f, 0.f};
    float4_t s1 = s0, s2 = s0, s3 = s0;
    {
      int sl0 = l16 * 8 + (quad ^ (l16 & 7));          // hs 0..31, key l16+{0,16,32,48}
      s0 = MFMA_BF16(qf0, *(const bfrag*)&Ks[(size_t)sl0 * 8], s0);
      s1 = MFMA_BF16(qf0, *(const bfrag*)&Ks[(size_t)(sl0 + 128) * 8], s1);
      s2 = MFMA_BF16(qf0, *(const bfrag*)&Ks[(size_t)(sl0 + 256) * 8], s2);
      s3 = MFMA_BF16(qf0, *(const bfrag*)&Ks[(size_t)(sl0 + 384) * 8], s3);
      int sl1 = l16 * 8 + ((4 + quad) ^ (l16 & 7));    // hs 32..63
      s0 = MFMA_BF16(qf1, *(const bfrag*)&Ks[(size_t)sl1 * 8], s0);
      s1 = MFMA_BF16(qf1, *(const bfrag*)&Ks[(size_t)(sl1 + 128) * 8], s1);
      s2 = MFMA_BF16(qf1, *(const bfrag*)&Ks[(size_t)(sl1 + 256) * 8], s2);
      s3 = MFMA_BF16(qf1, *(const bfrag*)&Ks[(size_t)(sl1 + 384) * 8], s3);
    }

    int qa = qt * 64 + w * 16 + quad * 4;
    int kb0 = kt * 64 + l16;
    for (int r = 0; r < 4; ++r) {
      float v0 = s0[r] * 0.125f, v1 = s1[r] * 0.125f;
      float v2 = s2[r] * 0.125f, v3 = s3[r] * 0.125f;
      if (kb0 > qa + r)      v0 = -1e30f;
      if (kb0 + 16 > qa + r) v1 = -1e30f;
      if (kb0 + 32 > qa + r) v2 = -1e30f;
      if (kb0 + 48 > qa + r) v3 = -1e30f;
      float tm = fmaxf(fmaxf(v0, v1), fmaxf(v2, v3));
      tm = fmaxf(tm, __shfl_xor(tm, 1));
      tm = fmaxf(tm, __shfl_xor(tm, 2));
      tm = fmaxf(tm, __shfl_xor(tm, 4));
      tm = fmaxf(tm, __shfl_xor(tm, 8));
      float nm = fmaxf(m_i[r], tm);
      float alpha = __expf(m_i[r] - nm);
      m_i[r] = nm;
      float p0 = __expf(v0 - nm), p1 = __expf(v1 - nm);
      float p2 = __expf(v2 - nm), p3 = __expf(v3 - nm);
      float rs = (p0 + p1) + (p2 + p3);
      rs += __shfl_xor(rs, 1);
      rs += __shfl_xor(rs, 2);
      rs += __shfl_xor(rs, 4);
      rs += __shfl_xor(rs, 8);
      l_i[r] = l_i[r] * alpha + rs;
      acc[0][r] *= alpha; acc[1][r] *= alpha; acc[2][r] *= alpha; acc[3][r] *= alpha;
      int pr = (quad * 4 + r) * 72 + l16;
      Pw[pr]      = f2bf(p0);
      Pw[pr + 16] = f2bf(p1);
      Pw[pr + 32] = f2bf(p2);
      Pw[pr + 48] = f2bf(p3);
    }
    // No barrier: Pw is this wave's private slice; intra-wave LDS write->read
    // ordering is architectural (lgkmcnt), same argument as the Es restage.
    bfrag pf0 = *(const bfrag*)&Pw[(size_t)l16 * 72 + quad * 8];        // keys 0..31
    bfrag pf1 = *(const bfrag*)&Pw[(size_t)l16 * 72 + 32 + quad * 8];   // keys 32..63
    for (int ht = 0; ht < 4; ++ht) {
      bfrag vf0 = *(const bfrag*)&VTs[(size_t)(ht * 16 + l16) * 72 + quad * 8];
      bfrag vf1 = *(const bfrag*)&VTs[(size_t)(ht * 16 + l16) * 72 + 32 + quad * 8];
      acc[ht] = MFMA_BF16(pf0, vf0, acc[ht]);
      acc[ht] = MFMA_BF16(pf1, vf1, acc[ht]);
    }
  }

  // o_final[b, g*512+gt, h*64+hs]
  int orow = b * 4096 + g * 512 + qt * 64 + w * 16 + quad * 4;
  for (int ht = 0; ht < 4; ++ht)
    for (int r = 0; r < 4; ++r)
      ob[(size_t)(orow + r) * 1024 + h * 64 + ht * 16 + l16] = f2bf(acc[ht][r] / l_i[r]);
}

// ---------------------------------------------------------------------------
// qb/kb/vb: weighted sums over gt (causal_attn on 1x1 == identity => vb pooled)
// 1024 threads/block, 16-way t-split + LDS reduce (validated R8).
__global__ __launch_bounds__(1024) void pools_kernel(const unsigned short* __restrict__ q5,
    const unsigned short* __restrict__ k5, const unsigned short* __restrict__ v5,
    const float* __restrict__ qp, const float* __restrict__ kp,
    const float* __restrict__ vp, float* __restrict__ outp) {
  __shared__ float red[3][16][64];
  int g = blockIdx.x, h = blockIdx.y, b = blockIdx.z;
  int hs = threadIdx.x & 63, tc = threadIdx.x >> 6;      // 16 chunks x 32 t
  size_t base = ((((size_t)b * 16 + h) * 8 + g) * 512) * 64 + hs;
  float aq = 0.f, ak = 0.f, av = 0.f;
  int t0 = tc * 32;
  for (int t = t0; t < t0 + 32; ++t) {
    size_t o = base + (size_t)t * 64;
    aq = fmaf(bf2f(q5[o]), qp[t], aq);
    ak = fmaf(bf2f(k5[o]), kp[t], ak);
    av = fmaf(bf2f(v5[o]), vp[t], av);
  }
  red[0][tc][hs] = aq;
  red[1][tc][hs] = ak;
  red[2][tc][hs] = av;
  __syncthreads();
  if (tc < 3) {                                          // tc: 0=q 1=k 2=v
    float a = 0.f;
    for (int c = 0; c < 16; ++c) a += red[tc][c][hs];
    size_t oi = (((size_t)b * 16 + h) * 7 + g) * 64 + hs;
    size_t off = (tc == 0) ? 0 : (tc == 1) ? 28672 : 57344;
    outp[16777216 + off + oi] = a;
  }
}

// ---------------------------------------------------------------------------
extern "C" void kernel_launch(void* const* d_in, const int* in_sizes, int n_in,
                              void* d_out, int out_size, void* d_ws, size_t ws_size,
                              hipStream_t stream) {
  (void)in_sizes; (void)n_in; (void)out_size; (void)ws_size;
  const float* x    = (const float*)d_in[0];
  const float* Wqkv = (const float*)d_in[1];
  const float* Wo   = (const float*)d_in[2];
  const float* qp   = (const float*)d_in[3];
  const float* kp   = (const float*)d_in[4];
  const float* vp   = (const float*)d_in[5];
  const float* fc   = (const float*)d_in[6];
  const float* fs   = (const float*)d_in[7];
  float* outp = (float*)d_out;                     // f32 output (reference dtype)

  char* ws = (char*)d_ws;                          // 136 MiB used
  unsigned short* xb    = (unsigned short*)(ws);               // 33.5MB (o aliases it later)
  unsigned short* wqkvT = (unsigned short*)(ws + 33554432);    // 6.3MB
  unsigned short* woT   = (unsigned short*)(ws + 39845888);    // 2.1MB
  unsigned short* q5    = (unsigned short*)(ws + 41943040);    // 33.5MB
  unsigned short* k5    = (unsigned short*)(ws + 75497472);    // 33.5MB
  unsigned short* v5    = (unsigned short*)(ws + 109051904);   // 33.5MB
  unsigned short* ob    = xb;  // safe alias: xb fully consumed by gemm1 before attn writes

  // fcT/fsT scratch lives in d_out[0 .. 512K floats): dead until gemm2, which
  // runs LAST and overwrites it. 32x4096 f32 each.
  float* fcT = outp;
  float* fsT = outp + 131072;

  cvt_kernel<<<8192, 256, 0, stream>>>(x, xb, 2097152);
  transpose_cvt_kernel<<<dim3(96, 32), dim3(32, 8), 0, stream>>>(Wqkv, wqkvT, 1024, 3072);
  transpose_cvt_kernel<<<dim3(32, 32), dim3(32, 8), 0, stream>>>(Wo, woT, 1024, 1024);
  transpose_f32_kernel<<<dim3(1, 128), dim3(32, 8), 0, stream>>>(fc, fcT, 4096, 32);
  transpose_f32_kernel<<<dim3(1, 128), dim3(32, 8), 0, stream>>>(fs, fsT, 4096, 32);
  gemm1_kernel<<<dim3(24, 128), 256, 0, stream>>>(xb, wqkvT, fcT, fsT, q5, k5, v5);
  attn_kernel<<<4096, 256, 0, stream>>>(q5, k5, v5, ob);
  pools_kernel<<<dim3(7, 16, 4), 1024, 0, stream>>>(q5, k5, v5, qp, kp, vp, outp);
  gemm2_kernel<<<dim3(8, 128), 256, 0, stream>>>(ob, woT, outp);
}

// Round 5
// 502.378 us; speedup vs baseline: 1.0771x; 1.0076x over previous
//
#include <hip/hip_runtime.h>

// ---------------------------------------------------------------------------
// CausalSelfAttention2: x@Wqkv -> rope+scramble -> 512x block-causal attn
//                        -> o@Wo ; plus learned time-pooled qb/kb/vb outputs.
// Sizes: B=4 T=4096 C=1024 H=16 G=8 HS=64 GT=512. d_out is FLOAT32.
// R11: attn KVBLK 64 -> 128 (same mechanism as R10's validated 32->64 step:
// softmax shfl-tree + barrier cost scales with #tiles, not #keys; tiles
// 36 -> 20 per (b,h,g)). LDS 26 -> 50 KB (3 blocks/CU). MFMA unchanged.
// fc/fs transposes merged into one launch (blockIdx.z selects table).
// gemm1/gemm2/pools untouched (R9/R10-validated).
// ---------------------------------------------------------------------------

typedef float  float4_t  __attribute__((ext_vector_type(4)));
typedef short  bfrag     __attribute__((ext_vector_type(8)));   // 8 bf16
typedef unsigned short ushort8 __attribute__((ext_vector_type(8)));

#define MFMA_BF16(A, B, C) __builtin_amdgcn_mfma_f32_16x16x32_bf16((A), (B), (C), 0, 0, 0)

__device__ __forceinline__ unsigned short f2bf(float f) {
  union { float f; unsigned u; } v; v.f = f;
  return (unsigned short)((v.u + 0x7FFFu + ((v.u >> 16) & 1u)) >> 16);   // RNE
}
__device__ __forceinline__ float bf2f(unsigned short h) {
  union { unsigned u; float f; } v; v.u = ((unsigned)h) << 16; return v.f;
}
// async global->LDS, 16B per lane; LDS dest = wave-uniform base + lane*16
__device__ __forceinline__ void async16(const void* g, void* l) {
  __builtin_amdgcn_global_load_lds(
      (const __attribute__((address_space(1))) unsigned int*)(unsigned long long)g,
      (__attribute__((address_space(3))) unsigned int*)(unsigned long long)l,
      16, 0, 0);
}

// ---------------------------------------------------------------------------
// f32 -> bf16 convert (8 elems/thread)
__global__ __launch_bounds__(256) void cvt_kernel(const float* __restrict__ in,
                                                  unsigned short* __restrict__ out, int n8) {
  int i = blockIdx.x * 256 + threadIdx.x;
  if (i >= n8) return;
  const float4_t* p = (const float4_t*)in + (size_t)i * 2;
  float4_t a = p[0], c = p[1];
  ushort8 r;
  r[0] = f2bf(a[0]); r[1] = f2bf(a[1]); r[2] = f2bf(a[2]); r[3] = f2bf(a[3]);
  r[4] = f2bf(c[0]); r[5] = f2bf(c[1]); r[6] = f2bf(c[2]); r[7] = f2bf(c[3]);
  *((ushort8*)out + i) = r;
}

// out[n][k] = bf16(in[k][n]);  in is [R,C] f32, out is [C,R] bf16
__global__ void transpose_cvt_kernel(const float* __restrict__ in,
                                     unsigned short* __restrict__ out, int R, int C) {
  __shared__ float t[32][33];
  int bc = blockIdx.x * 32, br = blockIdx.y * 32;
  int x = threadIdx.x, y = threadIdx.y;
  for (int i = 0; i < 32; i += 8) t[y + i][x] = in[(size_t)(br + y + i) * C + bc + x];
  __syncthreads();
  for (int i = 0; i < 32; i += 8) out[(size_t)(bc + y + i) * R + br + x] = f2bf(t[x][y + i]);
}

// out[n][k] = in[k][n]; f32 transpose of TWO tables (z selects), R=4096 C=32
__global__ void transpose2_f32_kernel(const float* __restrict__ a,
                                      const float* __restrict__ b,
                                      float* __restrict__ oa, float* __restrict__ ob_,
                                      int R, int C) {
  const float* in = blockIdx.z ? b : a;
  float* out = blockIdx.z ? ob_ : oa;
  __shared__ float t[32][33];
  int bc = blockIdx.x * 32, br = blockIdx.y * 32;
  int x = threadIdx.x, y = threadIdx.y;
  for (int i = 0; i < 32; i += 8) t[y + i][x] = in[(size_t)(br + y + i) * C + bc + x];
  __syncthreads();
  for (int i = 0; i < 32; i += 8) out[(size_t)(bc + y + i) * R + br + x] = t[x][y + i];
}

// ---------------------------------------------------------------------------
// Shared GEMM core: C128x128 tile, BK=32, 4 waves (each 64x64 = 4x4 mfma frags)
// A [M,K] bf16 row-major, BT [N,K] bf16 row-major. XOR-swizzled LDS (2-way max).
__device__ __forceinline__ void gemm_core(const unsigned short* __restrict__ A,
                                          const unsigned short* __restrict__ BT,
                                          int bm0, int bn0, int K,
                                          unsigned short* As, unsigned short* Bs,
                                          float4_t acc[4][4]) {
  int tid = threadIdx.x, w = tid >> 6;
  int lane = tid & 63, quad = lane >> 4, l16 = lane & 15;
  int wm = w >> 1, wn = w & 1;
  int rr = tid >> 2, xx = tid & 3;
  for (int k0 = 0; k0 < K; k0 += 32) {
    __syncthreads();
    {
      int r0 = rr,       s0 = xx ^ ((r0 >> 1) & 3);
      int r1 = rr + 64,  s1 = xx ^ ((r1 >> 1) & 3);
      async16(&A [(size_t)(bm0 + r0) * K + k0 + s0 * 8], &As[(size_t)(w * 64) * 8]);
      async16(&A [(size_t)(bm0 + r1) * K + k0 + s1 * 8], &As[(size_t)(256 + w * 64) * 8]);
      async16(&BT[(size_t)(bn0 + r0) * K + k0 + s0 * 8], &Bs[(size_t)(w * 64) * 8]);
      async16(&BT[(size_t)(bn0 + r1) * K + k0 + s1 * 8], &Bs[(size_t)(256 + w * 64) * 8]);
    }
    __syncthreads();
    bfrag af[4], bf_[4];
    for (int i = 0; i < 4; ++i) {
      int rm = wm * 64 + i * 16 + l16;
      af[i]  = *(const bfrag*)&As[(size_t)(rm * 4 + (quad ^ ((rm >> 1) & 3))) * 8];
      int rn = wn * 64 + i * 16 + l16;
      bf_[i] = *(const bfrag*)&Bs[(size_t)(rn * 4 + (quad ^ ((rn >> 1) & 3))) * 8];
    }
    for (int i = 0; i < 4; ++i)
      for (int j = 0; j < 4; ++j)
        acc[i][j] = MFMA_BF16(af[i], bf_[j], acc[i][j]);
  }
}

// GEMM1: qkv = x @ Wqkv. Rope applied in-register (R3-validated shfl form;
// fc/fs values read from transposed tables -> float4 loads, identical f32
// values & fma order), then LDS restage (placement validated) + vector stores.
__global__ __launch_bounds__(256) void gemm1_kernel(const unsigned short* __restrict__ xb,
    const unsigned short* __restrict__ wqkvT,
    const float* __restrict__ fcT, const float* __restrict__ fsT,
    unsigned short* __restrict__ q5, unsigned short* __restrict__ k5,
    unsigned short* __restrict__ v5) {
  __shared__ __align__(16) unsigned short As[128 * 32];
  __shared__ __align__(16) unsigned short Bs[128 * 32];
  __shared__ __align__(16) float Es[4 * 1088];               // 4 waves x (16 rows * 68)
  float4_t acc[4][4];
  for (int i = 0; i < 4; ++i) for (int j = 0; j < 4; ++j)
    acc[i][j] = (float4_t){0.f, 0.f, 0.f, 0.f};
  int bn0 = blockIdx.x * 128, bm0 = blockIdx.y * 128;
  gemm_core(xb, wqkvT, bm0, bn0, 1024, As, Bs, acc);

  int tid = threadIdx.x, w = tid >> 6, lane = tid & 63, quad = lane >> 4, l16 = lane & 15;
  int wm = w >> 1, wn = w & 1;

  // ---- rope in registers (R3 numerics; fcT/fsT float4 loads over r) -------
  for (int i = 0; i < 4; ++i) {
    int t0 = (bm0 + wm * 64 + i * 16 + quad * 4) & 4095;   // r spans t0..t0+3
    for (int j = 0; j < 4; ++j) {
      int gcol = bn0 + wn * 64 + j * 16 + l16;    // wave-uniform branch (16-aligned)
      if (gcol < 2048) {
        int ci = (gcol & 63) >> 1;                // pair index 0..31 (per lane)
        const float4_t c4 = *(const float4_t*)&fcT[(size_t)ci * 4096 + t0];
        const float4_t s4 = *(const float4_t*)&fsT[(size_t)ci * 4096 + t0];
        for (int r = 0; r < 4; ++r) {
          float val = acc[i][j][r];
          float partner = __shfl_xor(val, 1);     // even<->odd channel pair
          float c = c4[r], s = s4[r];             // == fc[t*32+ci], fs[t*32+ci]
          acc[i][j][r] = (gcol & 1) ? fmaf(partner, s, val * c)
                                    : fmaf(-partner, s, val * c);
        }
      }
    }
  }

  // ---- LDS restage (placement-validated) + full-line vector stores --------
  // Each wave uses its PRIVATE Es slice; intra-wave LDS write->read order is
  // architectural, so no barriers are needed here.
  float* slice = &Es[w * 1088];
  for (int i = 0; i < 4; ++i) {
    for (int j = 0; j < 4; ++j)
      for (int r = 0; r < 4; ++r)
        slice[(quad * 4 + r) * 68 + j * 16 + l16] = acc[i][j][r];
    for (int m = 0; m < 2; ++m) {
      int rl = m * 8 + (lane >> 3);               // 0..15 local row
      int cb = (lane & 7) * 8;                    // 8-aligned col base
      const float* rp = &slice[rl * 68 + cb];
      ushort8 outv;
      outv[0] = f2bf(rp[0]); outv[1] = f2bf(rp[1]);
      outv[2] = f2bf(rp[2]); outv[3] = f2bf(rp[3]);
      outv[4] = f2bf(rp[4]); outv[5] = f2bf(rp[5]);
      outv[6] = f2bf(rp[6]); outv[7] = f2bf(rp[7]);
      int grow = bm0 + wm * 64 + i * 16 + rl;     // = b*4096 + t
      int b = grow >> 12, t = grow & 4095;
      int gcol = bn0 + wn * 64 + cb;              // 0..3071, 8-aligned
      if (gcol < 2048) {                          // q or k: scramble
        int cc = gcol & 1023;
        int ho = cc >> 6, hs0 = cc & 63;
        // [B,H,T,HS] raw-view [B,G,GT,H,HS]: g=ho/2, gt=(ho&1)*256+t/16, h=t&15
        size_t idx = ((((size_t)b * 16 + (t & 15)) * 8 + (ho >> 1)) * 512 +
                      (((ho & 1) << 8) | (t >> 4))) * 64 + hs0;
        if (gcol < 1024) *(ushort8*)&q5[idx] = outv;
        else             *(ushort8*)&k5[idx] = outv;
      } else {                                    // v: natural split
        int cc = gcol - 2048;
        size_t idx = ((((size_t)b * 16 + (cc >> 6)) * 8 + (t >> 9)) * 512 +
                      (t & 511)) * 64 + (cc & 63);
        *(ushort8*)&v5[idx] = outv;
      }
    }
  }
}

// GEMM2: out = o @ Wo, f32 store into d_out[0 .. 16777216)
__global__ __launch_bounds__(256) void gemm2_kernel(const unsigned short* __restrict__ ob,
    const unsigned short* __restrict__ woT, float* __restrict__ outp) {
  __shared__ __align__(16) unsigned short As[128 * 32];
  __shared__ __align__(16) unsigned short Bs[128 * 32];
  float4_t acc[4][4];
  for (int i = 0; i < 4; ++i) for (int j = 0; j < 4; ++j)
    acc[i][j] = (float4_t){0.f, 0.f, 0.f, 0.f};
  int bn0 = blockIdx.x * 128, bm0 = blockIdx.y * 128;
  gemm_core(ob, woT, bm0, bn0, 1024, As, Bs, acc);
  int tid = threadIdx.x, w = tid >> 6, lane = tid & 63, quad = lane >> 4, l16 = lane & 15;
  int wm = w >> 1, wn = w & 1;
  for (int i = 0; i < 4; ++i)
    for (int j = 0; j < 4; ++j)
      for (int r = 0; r < 4; ++r)
        outp[(size_t)(bm0 + wm * 64 + i * 16 + quad * 4 + r) * 1024 +
             bn0 + wn * 64 + j * 16 + l16] = acc[i][j][r];
}

// ---------------------------------------------------------------------------
// MFMA flash attention per (b,h,g) block of 512, 64-query tile / wg, 16 q/wave.
// R11: 128-key K/V tiles. Per tile: 16 QK MFMA + 16 PV MFMA, one softmax
// pass (4 rows x 8 key-slots), 2 barriers. ntiles = (qt+2)>>1 (max 4).
__global__ __launch_bounds__(256) void attn_kernel(const unsigned short* __restrict__ q5,
    const unsigned short* __restrict__ k5, const unsigned short* __restrict__ v5,
    unsigned short* __restrict__ ob) {
  __shared__ __align__(16) unsigned short Ks[128 * 64];      // 1024 swizzled 16B slots
  __shared__ __align__(16) unsigned short VTs[64 * 136];     // [hs][key 0..127], pad->136
  __shared__ __align__(16) unsigned short Ps[4 * 16 * 136];  // per-wave P[16 q][128 k]
  int bx = blockIdx.x;
  int qt = bx & 7, g = (bx >> 3) & 7, h = (bx >> 6) & 15, b = bx >> 10;
  int tid = threadIdx.x, w = tid >> 6, lane = tid & 63, quad = lane >> 4, l16 = lane & 15;
  size_t base = ((((size_t)b * 16 + h) * 8 + g) * 512) * 64;
  const unsigned short* Q = q5 + base;
  const unsigned short* K = k5 + base;
  const unsigned short* V = v5 + base;

  int qrow = qt * 64 + w * 16 + l16;
  bfrag qf0 = *(const bfrag*)&Q[(size_t)qrow * 64 + quad * 8];
  bfrag qf1 = *(const bfrag*)&Q[(size_t)qrow * 64 + 32 + quad * 8];

  float4_t acc[4];
#pragma unroll
  for (int i = 0; i < 4; ++i) acc[i] = (float4_t){0.f, 0.f, 0.f, 0.f};
  float m_i[4] = {-1e30f, -1e30f, -1e30f, -1e30f};
  float l_i[4] = {0.f, 0.f, 0.f, 0.f};

  int skey = tid >> 3, sx = tid & 7, ss = sx ^ (skey & 7);   // K staging swizzle
  int kp = tid & 63, hsg = tid >> 6;                          // V staging split
  unsigned short* Pw = &Ps[w * 2176];                         // 16*136
  int ntiles = (qt + 2) >> 1;

  for (int kt = 0; kt < ntiles; ++kt) {
    __syncthreads();
    // K tile 128x64: four async16 per thread (rows skey+32c; XOR swizzle
    // index identical since (+32c) preserves row&7).
#pragma unroll
    for (int c = 0; c < 4; ++c)
      async16(&K[(size_t)(kt * 128 + 32 * c + skey) * 64 + ss * 8],
              &Ks[(size_t)(c * 256 + w * 64) * 8]);
    // V tile transposed into VTs[hs][key]: 256 threads, 2 keys x 16 hs each
    {
      const unsigned short* vp0 = &V[(size_t)(kt * 128 + kp * 2) * 64 + hsg * 16];
      ushort8 va0 = *(const ushort8*)vp0;
      ushort8 va1 = *(const ushort8*)(vp0 + 8);
      ushort8 vb0 = *(const ushort8*)(vp0 + 64);
      ushort8 vb1 = *(const ushort8*)(vp0 + 72);
#pragma unroll
      for (int e = 0; e < 8; ++e) {
        *(unsigned*)&VTs[(size_t)(hsg * 16 + e) * 136 + kp * 2] =
            (unsigned)va0[e] | ((unsigned)vb0[e] << 16);
        *(unsigned*)&VTs[(size_t)(hsg * 16 + 8 + e) * 136 + kp * 2] =
            (unsigned)va1[e] | ((unsigned)vb1[e] << 16);
      }
    }
    __syncthreads();

    float4_t s[8];
#pragma unroll
    for (int c = 0; c < 8; ++c) s[c] = (float4_t){0.f, 0.f, 0.f, 0.f};
    {
      int sl0 = l16 * 8 + (quad ^ (l16 & 7));          // hs 0..31, key l16+16c
      int sl1 = l16 * 8 + ((4 + quad) ^ (l16 & 7));    // hs 32..63
#pragma unroll
      for (int c = 0; c < 8; ++c) {
        s[c] = MFMA_BF16(qf0, *(const bfrag*)&Ks[(size_t)(sl0 + 128 * c) * 8], s[c]);
        s[c] = MFMA_BF16(qf1, *(const bfrag*)&Ks[(size_t)(sl1 + 128 * c) * 8], s[c]);
      }
    }

    int qa = qt * 64 + w * 16 + quad * 4;
    int kb0 = kt * 128 + l16;
#pragma unroll
    for (int r = 0; r < 4; ++r) {
      float vv[8];
#pragma unroll
      for (int c = 0; c < 8; ++c) {
        vv[c] = s[c][r] * 0.125f;
        if (kb0 + 16 * c > qa + r) vv[c] = -1e30f;
      }
      float tm = fmaxf(fmaxf(fmaxf(vv[0], vv[1]), fmaxf(vv[2], vv[3])),
                       fmaxf(fmaxf(vv[4], vv[5]), fmaxf(vv[6], vv[7])));
      tm = fmaxf(tm, __shfl_xor(tm, 1));
      tm = fmaxf(tm, __shfl_xor(tm, 2));
      tm = fmaxf(tm, __shfl_xor(tm, 4));
      tm = fmaxf(tm, __shfl_xor(tm, 8));
      float nm = fmaxf(m_i[r], tm);
      float alpha = __expf(m_i[r] - nm);
      m_i[r] = nm;
      float p[8], rs = 0.f;
#pragma unroll
      for (int c = 0; c < 8; ++c) { p[c] = __expf(vv[c] - nm); rs += p[c]; }
      rs += __shfl_xor(rs, 1);
      rs += __shfl_xor(rs, 2);
      rs += __shfl_xor(rs, 4);
      rs += __shfl_xor(rs, 8);
      l_i[r] = l_i[r] * alpha + rs;
      acc[0][r] *= alpha; acc[1][r] *= alpha; acc[2][r] *= alpha; acc[3][r] *= alpha;
      int pr = (quad * 4 + r) * 136 + l16;
#pragma unroll
      for (int c = 0; c < 8; ++c) Pw[pr + 16 * c] = f2bf(p[c]);
    }
    // No barrier: Pw is this wave's private slice; intra-wave LDS write->read
    // ordering is architectural (lgkmcnt), same argument as the Es restage.
    bfrag pf[4];
#pragma unroll
    for (int c = 0; c < 4; ++c)
      pf[c] = *(const bfrag*)&Pw[(size_t)l16 * 136 + 32 * c + quad * 8];
#pragma unroll
    for (int ht = 0; ht < 4; ++ht) {
#pragma unroll
      for (int c = 0; c < 4; ++c) {
        bfrag vf = *(const bfrag*)&VTs[(size_t)(ht * 16 + l16) * 136 + 32 * c + quad * 8];
        acc[ht] = MFMA_BF16(pf[c], vf, acc[ht]);
      }
    }
  }

  // o_final[b, g*512+gt, h*64+hs]
  int orow = b * 4096 + g * 512 + qt * 64 + w * 16 + quad * 4;
#pragma unroll
  for (int ht = 0; ht < 4; ++ht)
#pragma unroll
    for (int r = 0; r < 4; ++r)
      ob[(size_t)(orow + r) * 1024 + h * 64 + ht * 16 + l16] = f2bf(acc[ht][r] / l_i[r]);
}

// ---------------------------------------------------------------------------
// qb/kb/vb: weighted sums over gt (causal_attn on 1x1 == identity => vb pooled)
// 1024 threads/block, 16-way t-split + LDS reduce (validated R8).
__global__ __launch_bounds__(1024) void pools_kernel(const unsigned short* __restrict__ q5,
    const unsigned short* __restrict__ k5, const unsigned short* __restrict__ v5,
    const float* __restrict__ qp, const float* __restrict__ kp,
    const float* __restrict__ vp, float* __restrict__ outp) {
  __shared__ float red[3][16][64];
  int g = blockIdx.x, h = blockIdx.y, b = blockIdx.z;
  int hs = threadIdx.x & 63, tc = threadIdx.x >> 6;      // 16 chunks x 32 t
  size_t base = ((((size_t)b * 16 + h) * 8 + g) * 512) * 64 + hs;
  float aq = 0.f, ak = 0.f, av = 0.f;
  int t0 = tc * 32;
  for (int t = t0; t < t0 + 32; ++t) {
    size_t o = base + (size_t)t * 64;
    aq = fmaf(bf2f(q5[o]), qp[t], aq);
    ak = fmaf(bf2f(k5[o]), kp[t], ak);
    av = fmaf(bf2f(v5[o]), vp[t], av);
  }
  red[0][tc][hs] = aq;
  red[1][tc][hs] = ak;
  red[2][tc][hs] = av;
  __syncthreads();
  if (tc < 3) {                                          // tc: 0=q 1=k 2=v
    float a = 0.f;
    for (int c = 0; c < 16; ++c) a += red[tc][c][hs];
    size_t oi = (((size_t)b * 16 + h) * 7 + g) * 64 + hs;
    size_t off = (tc == 0) ? 0 : (tc == 1) ? 28672 : 57344;
    outp[16777216 + off + oi] = a;
  }
}

// ---------------------------------------------------------------------------
extern "C" void kernel_launch(void* const* d_in, const int* in_sizes, int n_in,
                              void* d_out, int out_size, void* d_ws, size_t ws_size,
                              hipStream_t stream) {
  (void)in_sizes; (void)n_in; (void)out_size; (void)ws_size;
  const float* x    = (const float*)d_in[0];
  const float* Wqkv = (const float*)d_in[1];
  const float* Wo   = (const float*)d_in[2];
  const float* qp   = (const float*)d_in[3];
  const float* kp   = (const float*)d_in[4];
  const float* vp   = (const float*)d_in[5];
  const float* fc   = (const float*)d_in[6];
  const float* fs   = (const float*)d_in[7];
  float* outp = (float*)d_out;                     // f32 output (reference dtype)

  char* ws = (char*)d_ws;                          // 136 MiB used
  unsigned short* xb    = (unsigned short*)(ws);               // 33.5MB (o aliases it later)
  unsigned short* wqkvT = (unsigned short*)(ws + 33554432);    // 6.3MB
  unsigned short* woT   = (unsigned short*)(ws + 39845888);    // 2.1MB
  unsigned short* q5    = (unsigned short*)(ws + 41943040);    // 33.5MB
  unsigned short* k5    = (unsigned short*)(ws + 75497472);    // 33.5MB
  unsigned short* v5    = (unsigned short*)(ws + 109051904);   // 33.5MB
  unsigned short* ob    = xb;  // safe alias: xb fully consumed by gemm1 before attn writes

  // fcT/fsT scratch lives in d_out[0 .. 512K floats): dead until gemm2, which
  // runs LAST and overwrites it. 32x4096 f32 each.
  float* fcT = outp;
  float* fsT = outp + 131072;

  cvt_kernel<<<8192, 256, 0, stream>>>(x, xb, 2097152);
  transpose_cvt_kernel<<<dim3(96, 32), dim3(32, 8), 0, stream>>>(Wqkv, wqkvT, 1024, 3072);
  transpose_cvt_kernel<<<dim3(32, 32), dim3(32, 8), 0, stream>>>(Wo, woT, 1024, 1024);
  transpose2_f32_kernel<<<dim3(1, 128, 2), dim3(32, 8), 0, stream>>>(fc, fs, fcT, fsT, 4096, 32);
  gemm1_kernel<<<dim3(24, 128), 256, 0, stream>>>(xb, wqkvT, fcT, fsT, q5, k5, v5);
  attn_kernel<<<4096, 256, 0, stream>>>(q5, k5, v5, ob);
  pools_kernel<<<dim3(7, 16, 4), 1024, 0, stream>>>(q5, k5, v5, qp, kp, vp, outp);
  gemm2_kernel<<<dim3(8, 128), 256, 0, stream>>>(ob, woT, outp);
}